// Round 3
// baseline (7072.482 us; speedup 1.0000x reference)
//
#include <hip/hip_runtime.h>
#include <hip/hip_fp16.h>

typedef _Float16 half8 __attribute__((ext_vector_type(8)));
typedef float    float4_ __attribute__((ext_vector_type(4)));

#define TSTEPS 512
#define NA 64
#define NB 128
#define NC 8
#define FSTRIDE 32                // ints per flag slot = 128 B (own cache line)

// workspace layout (bytes) — IDENTICAL to the proven R1 layout (9.47 MB)
#define FLA_OFF   0               // 64 flags  x 128 B
#define FLB_OFF   8192            // 128 flags x 128 B
#define FLC_OFF   24576           // 8 flags   x 128 B
#define H1_OFF    32768
#define H1_PHASE  262144          // one phase: 1024 cols x 128 batch x 2B, fragment-major
#define H2_OFF    (H1_OFF + 2 * H1_PHASE)
#define X_OFF     (H2_OFF + 2 * H1_PHASE)
#define X_TSTRIDE 16384           // 64 cols x 128 batch x 2B per step
#define ZERO_BYTES X_OFF          // flags + H1 + H2 zeroed each call

// fast activations: v_rcp_f32 (~1e-7 rel) + v_exp; h is fp16 anyway
__device__ __forceinline__ float fastrcp(float x) {
    float r; asm("v_rcp_f32 %0, %1" : "=v"(r) : "v"(x)); return r;
}
__device__ __forceinline__ float sigf(float x)  { return fastrcp(1.0f + __expf(-x)); }
__device__ __forceinline__ float tanh_(float x) { return 1.0f - 2.0f * fastrcp(1.0f + __expf(2.0f * x)); }

__device__ __forceinline__ half8 zero8() {
    half8 z;
#pragma unroll
    for (int j = 0; j < 8; ++j) z[j] = (_Float16)0.0f;
    return z;
}

__device__ __forceinline__ half8 wfrag_load(const float* Wa, int lda,
                                            const float* Wb, int ldb,
                                            int split, int row, int k0) {
    const float* s = (k0 < split) ? (Wa + (size_t)row * lda + k0)
                                  : (Wb + (size_t)row * ldb + (k0 - split));
    float4_ lo = *(const float4_*)s;
    float4_ hi = *(const float4_*)(s + 4);
    half8 r;
    r[0] = (_Float16)lo[0]; r[1] = (_Float16)lo[1];
    r[2] = (_Float16)lo[2]; r[3] = (_Float16)lo[3];
    r[4] = (_Float16)hi[0]; r[5] = (_Float16)hi[1];
    r[6] = (_Float16)hi[2]; r[7] = (_Float16)hi[3];
    return r;
}

// ---- coherence-point access primitives (NO fences, NO buffer_inv/wbl2) ----

// 16B device-scope-coherent plain load (sc1). Consumer must pass the value
// through a VMWAIT* fence below before use (compiler inserts no waitcnt).
__device__ __forceinline__ half8 ldg_sc1_16(const void* p) {
    half8 r;
    asm volatile("global_load_dwordx4 %0, %1, off sc1" : "=v"(r) : "v"(p));
    return r;
}

#define VMWAIT8(A) asm volatile("s_waitcnt vmcnt(0)" : \
    "+v"((A)[0]), "+v"((A)[1]), "+v"((A)[2]), "+v"((A)[3]), \
    "+v"((A)[4]), "+v"((A)[5]), "+v"((A)[6]), "+v"((A)[7]) :: "memory")

// counted waits: wait until at most N vmem ops outstanding, tying ONLY the
// group being released (loads complete in issue order).
#define VMWAIT9_N(A, NS) asm volatile("s_waitcnt vmcnt(" NS ")" : \
    "+v"((A)[0]), "+v"((A)[1]), "+v"((A)[2]), "+v"((A)[3]), "+v"((A)[4]), \
    "+v"((A)[5]), "+v"((A)[6]), "+v"((A)[7]), "+v"((A)[8]) :: "memory")
#define VMWAIT8_N(A, NS) asm volatile("s_waitcnt vmcnt(" NS ")" : \
    "+v"((A)[0]), "+v"((A)[1]), "+v"((A)[2]), "+v"((A)[3]), \
    "+v"((A)[4]), "+v"((A)[5]), "+v"((A)[6]), "+v"((A)[7]) :: "memory")

// 16B write-through store (sc0 sc1): full-line-coalescable publish store.
__device__ __forceinline__ void stg_coh_16(void* p, float4_ v) {
    asm volatile("global_store_dwordx4 %0, %1, off sc0 sc1" :: "v"(p), "v"(v) : "memory");
}

__device__ __forceinline__ void stg_coh_int(void* p, int v) {
    asm volatile("global_store_dword %0, %1, off sc0 sc1" :: "v"(p), "v"(v) : "memory");
}

// producer-side ordering: my write-through stores acked (vmcnt 0), then block
// barrier, then (thread 0) flag store.
__device__ __forceinline__ void publish(int* fbase, int idx, int v) {
    asm volatile("s_waitcnt vmcnt(0)" ::: "memory");
    __syncthreads();
    if (threadIdx.x == 0) stg_coh_int(fbase + idx * FSTRIDE, v);
}

__device__ __forceinline__ int ld_flag(const int* f, int idx) {
    return __hip_atomic_load(f + idx * FSTRIDE, __ATOMIC_RELAXED,
                             __HIP_MEMORY_SCOPE_AGENT);
}

// staging-image chunk swizzle: permutes 16B chunks, bank-spreads the
// per-column scattered 2B writes while keeping 16B read contiguity.
__device__ __forceinline__ int swz(int u) {
    return u ^ (((u >> 3) ^ (u >> 7)) & 7);
}

// Convert input [128 b][512 t][64 i] fp32 -> fragment-major fp16 X[t][kt][quad][b][j]
extern "C" __global__ void prep_x(const float* __restrict__ in, char* __restrict__ ws) {
    const int t = blockIdx.x;
    char* X = ws + X_OFF + (size_t)t * X_TSTRIDE;
    for (int idx = threadIdx.x; idx < 8192; idx += 256) {
        int kt = idx >> 12, rem = idx & 4095;
        int quad = rem >> 10, rem2 = rem & 1023;
        int b = rem2 >> 3, j = rem2 & 7;
        int i = kt * 32 + quad * 8 + j;
        float v = in[(size_t)b * 32768 + (size_t)t * 64 + i];
        *(_Float16*)(X + (size_t)idx * 2) = (_Float16)v;
    }
}

extern "C" __global__ __launch_bounds__(256, 1)
void lstm_persistent(const float* __restrict__ Wih1, const float* __restrict__ Whh1,
                     const float* __restrict__ bih1, const float* __restrict__ bhh1,
                     const float* __restrict__ Wih2, const float* __restrict__ Whh2,
                     const float* __restrict__ bih2, const float* __restrict__ bhh2,
                     const float* __restrict__ Wout, const float* __restrict__ bout,
                     char* __restrict__ ws, float* __restrict__ out) {
    const int tid = threadIdx.x;
    const int w = tid >> 6, lane = tid & 63;
    const int quad = lane >> 4, cl = lane & 15;
    const int laneoff = quad * 2048 + cl * 16;
    int* fA = (int*)(ws + FLA_OFF);
    int* fB = (int*)(ws + FLB_OFF);
    int* fC = (int*)(ws + FLC_OFF);
    char* H1 = ws + H1_OFF;
    char* H2 = ws + H2_OFF;
    char* X  = ws + X_OFF;
    const int blk = blockIdx.x;
    // reduction scratch (48 KiB, 12 compact slots) + staging image (4 KiB)
    __shared__ __align__(16) char smem[53248];
    float4_* red = (float4_*)smem;
    unsigned short* stg = (unsigned short*)(smem + 49152);

    if (blk < NA) {
        // ---------- layer-1: h1 cols [c0,c0+16), K = 1088 (34 k-tiles), waves split K
        const int c0 = blk * 16;
        const int kbase = w * 9;
        // producer A-blocks for this wave's k-tiles (h1 cols)
        int g0 = kbase < 2 ? 2 : kbase;
        int g1 = kbase + 8; if (g1 > 33) g1 = 33;
        const int pf = 2 * (g0 - 2);
        const int pc = 2 * (g1 - 2) + 1 - pf + 1;
        half8 wfr[4][9];
#pragma unroll
        for (int nt = 0; nt < 4; ++nt) {
            int row = nt * 1024 + c0 + cl;
#pragma unroll
            for (int kk = 0; kk < 9; ++kk) {
                int ktg = kbase + kk;
                if (ktg < 34) wfr[nt][kk] = wfrag_load(Wih1, 64, Whh1, 1024, 64, row, ktg * 32 + quad * 8);
                else          wfr[nt][kk] = zero8();
            }
        }
        float ba[4];
#pragma unroll
        for (int g = 0; g < 4; ++g) ba[g] = bih1[g * 1024 + c0 + cl] + bhh1[g * 1024 + c0 + cl];
        float cst[2][4];
#pragma unroll
        for (int mi = 0; mi < 2; ++mi)
#pragma unroll
            for (int r = 0; r < 4; ++r) cst[mi][r] = 0.0f;

        for (int t = 0; t < TSTEPS; ++t) {
            // per-wave wait: my producers' h1[t-1] ready (fA >= t); phase (t&1)
            // free of B-readers (fB >= t-1; lanes 18..49 hold this wave's slice).
            // Union over 4 waves covers ALL fA and ALL fB -> block-level write
            // precondition is complete before the (barrier-gated) stores.
            for (;;) {
                bool ok = true;
                if (lane < pc)                      ok = ld_flag(fA, pf + lane) >= t;
                else if (lane >= 18 && lane < 50)   ok = ld_flag(fB, w * 32 + lane - 18) >= t - 1;
                if (__all(ok)) break;
                __builtin_amdgcn_s_sleep(1);
            }

            const char* xb  = X + (size_t)t * X_TSTRIDE;
            const char* h1r = H1 + (((t & 1) ^ 1) ? H1_PHASE : 0);
            char*       h1w = H1 + ((t & 1) ? H1_PHASE : 0);
            const char* kb[9];
#pragma unroll
            for (int kk = 0; kk < 9; ++kk) {
                int ktg = kbase + kk; if (ktg > 33) ktg = 33;
                kb[kk] = (ktg < 2) ? (xb + ktg * 8192) : (h1r + (ktg - 2) * 8192);
            }
            // 3-buffer, distance-2 prefetch with counted waits
            half8 af[3][9];
#pragma unroll
            for (int g = 0; g < 2; ++g)
#pragma unroll
                for (int kk = 0; kk < 9; ++kk)
                    af[g][kk] = ldg_sc1_16(kb[kk] + laneoff + g * 256);
            float4_ acc[8][4];
#pragma unroll
            for (int mt = 0; mt < 8; ++mt)
#pragma unroll
                for (int nt = 0; nt < 4; ++nt) acc[mt][nt] = (float4_){0.f, 0.f, 0.f, 0.f};
#pragma unroll
            for (int mt = 0; mt < 8; ++mt) {
                const int cur = mt % 3;
                if (mt < 7) { VMWAIT9_N(af[cur], "9"); }
                else        { VMWAIT9_N(af[cur], "0"); }
                if (mt < 6) {
                    const int nx = (mt + 2) % 3;
#pragma unroll
                    for (int kk = 0; kk < 9; ++kk)
                        af[nx][kk] = ldg_sc1_16(kb[kk] + laneoff + (mt + 2) * 256);
                }
#pragma unroll
                for (int kk = 0; kk < 9; ++kk)
#pragma unroll
                    for (int nt = 0; nt < 4; ++nt)
                        acc[mt][nt] = __builtin_amdgcn_mfma_f32_16x16x32_f16(
                            af[cur][kk], wfr[nt][kk], acc[mt][nt], 0, 0, 0);
            }
            // two-pass one-shot reduction through a 48 KiB compact buffer:
            // pass mi: every wave writes foreign partials once, 1 barrier,
            // owner sums. 3 barriers total (vs 8 for the sequenced version).
            float4_ mine[2][4];
#pragma unroll
            for (int mi = 0; mi < 2; ++mi) {
                if (mi) __syncthreads();  // protect buffer reuse across passes
#pragma unroll
                for (int r = 0; r < 4; ++r) if (r != w) {
                    const int slot = r * 3 + (w < r ? w : w - 1);
#pragma unroll
                    for (int nt = 0; nt < 4; ++nt)
                        red[(slot * 4 + nt) * 64 + lane] = acc[2 * r + mi][nt];
                }
                __syncthreads();
#pragma unroll
                for (int nt = 0; nt < 4; ++nt) {
                    float4_ s = acc[2 * w + mi][nt];
#pragma unroll
                    for (int src = 0; src < 3; ++src)
                        s += red[((w * 3 + src) * 4 + nt) * 64 + lane];
                    mine[mi][nt] = s;
                }
            }
            // nonlinearity -> swizzled staging image of the fragment-major dest
#pragma unroll
            for (int mi = 0; mi < 2; ++mi) {
#pragma unroll
                for (int r = 0; r < 4; ++r) {
                    float iv = mine[mi][0][r] + ba[0];
                    float fv = mine[mi][1][r] + ba[1];
                    float gv = mine[mi][2][r] + ba[2];
                    float ov = mine[mi][3][r] + ba[3];
                    float c = sigf(fv) * cst[mi][r] + sigf(iv) * tanh_(gv);
                    float h = sigf(ov) * tanh_(c);
                    cst[mi][r] = c;
                    int m = (2 * w + mi) * 16 + quad * 4 + r;
                    int u = ((cl >> 3) << 7) + m;
                    union { _Float16 hh; unsigned short us; } uu;
                    uu.hh = (_Float16)h;
                    stg[swz(u) * 8 + (cl & 7)] = uu.us;
                }
            }
            __syncthreads();
            // coalesced publish: one 16B full-line-combinable store per thread
            {
                const int g = tid >> 7, b = tid & 127;
                int u = (g << 7) + b;
                float4_ v = *(const float4_*)(stg + swz(u) * 8);
                char* dst = h1w + ((c0 >> 5) << 13) + ((((c0 >> 3) + g) & 3) << 11) + (b << 4);
                stg_coh_16(dst, v);
            }
            publish(fA, blk, t + 1);
        }
    } else if (blk < NA + NB) {
        // ---------- layer-2: h2 cols [c0,c0+8), K = 2048 (64 k-tiles), waves split K
        const int bb = blk - NA;
        const int c0 = bb * 8;
        const int kbase = w * 16;
        const int colB = c0 + (cl & 7);
        const int row0 = (cl < 8) ? colB : (1024 + colB);
        const int row1 = (cl < 8) ? (2048 + colB) : (3072 + colB);
        half8 wfr[2][16];
#pragma unroll
        for (int kk = 0; kk < 16; ++kk) {
            int k0 = (kbase + kk) * 32 + quad * 8;
            wfr[0][kk] = wfrag_load(Wih2, 1024, Whh2, 1024, 1024, row0, k0);
            wfr[1][kk] = wfrag_load(Wih2, 1024, Whh2, 1024, 1024, row1, k0);
        }
        const float bi = bih2[colB] + bhh2[colB];
        const float bf = bih2[1024 + colB] + bhh2[1024 + colB];
        const float bg = bih2[2048 + colB] + bhh2[2048 + colB];
        const float bo = bih2[3072 + colB] + bhh2[3072 + colB];
        float cst[2][4];
#pragma unroll
        for (int mi = 0; mi < 2; ++mi)
#pragma unroll
            for (int r = 0; r < 4; ++r) cst[mi][r] = 0.0f;
        const bool lolane = (cl & 8) == 0;

        for (int t = 0; t < TSTEPS; ++t) {
            // per-wave wait: w0/w1 cover fA[0..63] >= t+1 (h1[t] cols they read);
            // w0 also covers fC >= t-1 (phase free); w2/w3 cover fB[all] >= t.
            for (;;) {
                bool ok = true;
                if (w < 2) {
                    if (lane < 32)                    ok = ld_flag(fA, w * 32 + lane) >= t + 1;
                    else if (w == 0 && lane < 40)     ok = ld_flag(fC, lane - 32) >= t - 1;
                } else {
                    ok = ld_flag(fB, (w - 2) * 64 + lane) >= t;
                }
                if (__all(ok)) break;
                __builtin_amdgcn_s_sleep(1);
            }

            const char* h1c = H1 + ((t & 1) ? H1_PHASE : 0);
            const char* h2r = H2 + (((t & 1) ^ 1) ? H1_PHASE : 0);
            char*       h2w = H2 + ((t & 1) ? H1_PHASE : 0);
            const char* kb[16];
#pragma unroll
            for (int kk = 0; kk < 16; ++kk) {
                int ktg = kbase + kk;
                kb[kk] = (ktg < 32) ? (h1c + ktg * 8192) : (h2r + (ktg - 32) * 8192);
            }
            float4_ acc[8][2];
#pragma unroll
            for (int mt = 0; mt < 8; ++mt) {
                acc[mt][0] = (float4_){0.f, 0.f, 0.f, 0.f};
                acc[mt][1] = (float4_){0.f, 0.f, 0.f, 0.f};
            }
            // 4-buffer, sub-groups of 8 loads, distance-3 prefetch, counted waits.
            half8 af[4][8];
#pragma unroll
            for (int s = 0; s < 3; ++s)
#pragma unroll
                for (int k2 = 0; k2 < 8; ++k2)
                    af[s][k2] = ldg_sc1_16(kb[(s & 1) * 8 + k2] + laneoff + (s >> 1) * 256);
#pragma unroll
            for (int s = 0; s < 16; ++s) {
                const int cur = s & 3;
                if (s < 14)      { VMWAIT8_N(af[cur], "16"); }
                else if (s == 14){ VMWAIT8_N(af[cur], "8");  }
                else             { VMWAIT8_N(af[cur], "0");  }
                if (s < 13) {
                    const int nx = (s + 3) & 3;
#pragma unroll
                    for (int k2 = 0; k2 < 8; ++k2)
                        af[nx][k2] = ldg_sc1_16(kb[((s + 3) & 1) * 8 + k2] + laneoff + ((s + 3) >> 1) * 256);
                }
                const int mt = s >> 1, hb = (s & 1) * 8;
#pragma unroll
                for (int k2 = 0; k2 < 8; ++k2) {
                    acc[mt][0] = __builtin_amdgcn_mfma_f32_16x16x32_f16(af[cur][k2], wfr[0][hb + k2], acc[mt][0], 0, 0, 0);
                    acc[mt][1] = __builtin_amdgcn_mfma_f32_16x16x32_f16(af[cur][k2], wfr[1][hb + k2], acc[mt][1], 0, 0, 0);
                }
            }
            // one-shot reduction (24 KiB), single pass
#pragma unroll
            for (int r = 0; r < 4; ++r) if (r != w) {
                const int slot = r * 3 + (w < r ? w : w - 1);
#pragma unroll
                for (int mi = 0; mi < 2; ++mi)
#pragma unroll
                    for (int nt = 0; nt < 2; ++nt)
                        red[((slot * 2 + mi) * 2 + nt) * 64 + lane] = acc[2 * r + mi][nt];
            }
            __syncthreads();
            float4_ mine[2][2];
#pragma unroll
            for (int mi = 0; mi < 2; ++mi)
#pragma unroll
                for (int nt = 0; nt < 2; ++nt) {
                    float4_ s = acc[2 * w + mi][nt];
#pragma unroll
                    for (int src = 0; src < 3; ++src)
                        s += red[(((w * 3 + src) * 2 + mi) * 2 + nt) * 64 + lane];
                    mine[mi][nt] = s;
                }
#pragma unroll
            for (int mi = 0; mi < 2; ++mi) {
#pragma unroll
                for (int r = 0; r < 4; ++r) {
                    float d0 = mine[mi][0][r], d1 = mine[mi][1][r];
                    float s0 = __shfl_xor(d0, 8, 64);
                    float s1 = __shfl_xor(d1, 8, 64);
                    float iv = (lolane ? d0 : s0) + bi;
                    float fv = (lolane ? s0 : d0) + bf;
                    float gv = (lolane ? d1 : s1) + bg;
                    float ov = (lolane ? s1 : d1) + bo;
                    float c = sigf(fv) * cst[mi][r] + sigf(iv) * tanh_(gv);
                    float h = sigf(ov) * tanh_(c);
                    cst[mi][r] = c;
                    if (lolane) {
                        int m = (2 * w + mi) * 16 + quad * 4 + r;
                        union { _Float16 hh; unsigned short uss; } uu;
                        uu.hh = (_Float16)h;
                        stg[swz(m) * 8 + (cl & 7)] = uu.uss;
                    }
                }
            }
            __syncthreads();
            if (tid < 128) {
                const int b = tid;
                float4_ v = *(const float4_*)(stg + swz(b) * 8);
                char* dst = h2w + ((c0 >> 5) << 13) + (((c0 >> 3) & 3) << 11) + (b << 4);
                stg_coh_16(dst, v);
            }
            publish(fB, bb, t + 1);
        }
    } else {
        // ---------- output: batch tile cb, y = h2 @ Wout^T + bout, K = 1024
        const int cb = blk - NA - NB;
        const int kbase = w * 8;
        half8 wfr[4][8];
#pragma unroll
        for (int nt = 0; nt < 4; ++nt) {
            int row = nt * 16 + cl;
#pragma unroll
            for (int kk = 0; kk < 8; ++kk)
                wfr[nt][kk] = wfrag_load(Wout, 1024, Wout, 1024, 1 << 30, row, (kbase + kk) * 32 + quad * 8);
        }
        const float bo_ = bout[w * 16 + cl];

        for (int t = 0; t < TSTEPS; ++t) {
            // per-wave wait: my 32 B-producers at fB >= t+1 (h2[t] cols I read)
            for (;;) {
                bool ok = (lane < 32) ? (ld_flag(fB, w * 32 + lane) >= t + 1) : true;
                if (__all(ok)) break;
                __builtin_amdgcn_s_sleep(1);
            }
            const char* h2c = H2 + ((t & 1) ? H1_PHASE : 0);
            float4_ acc[4];
#pragma unroll
            for (int nt = 0; nt < 4; ++nt) acc[nt] = (float4_){0.f, 0.f, 0.f, 0.f};
            half8 af[8];
#pragma unroll
            for (int kk = 0; kk < 8; ++kk)
                af[kk] = ldg_sc1_16(h2c + (kbase + kk) * 8192 + laneoff + cb * 256);
            VMWAIT8(af);
#pragma unroll
            for (int kk = 0; kk < 8; ++kk)
#pragma unroll
                for (int nt = 0; nt < 4; ++nt)
                    acc[nt] = __builtin_amdgcn_mfma_f32_16x16x32_f16(af[kk], wfr[nt][kk], acc[nt], 0, 0, 0);
            // one-shot reduction (12 KiB)
#pragma unroll
            for (int r = 0; r < 4; ++r) if (r != w) {
                const int slot = r * 3 + (w < r ? w : w - 1);
                red[slot * 64 + lane] = acc[r];
            }
            __syncthreads();
            float4_ myy = acc[0];
#pragma unroll
            for (int r = 1; r < 4; ++r) if (w == r) myy = acc[r];
#pragma unroll
            for (int src = 0; src < 3; ++src)
                myy += red[(w * 3 + src) * 64 + lane];
#pragma unroll
            for (int r = 0; r < 4; ++r) {
                int m = cb * 16 + quad * 4 + r;
                out[(size_t)m * 32768 + (size_t)t * 64 + (w * 16 + cl)] = myy[r] + bo_;
            }
            publish(fC, cb, t + 1);
        }
    }
}

extern "C" void kernel_launch(void* const* d_in, const int* in_sizes, int n_in,
                              void* d_out, int out_size, void* d_ws, size_t ws_size,
                              hipStream_t stream) {
    const float* inp  = (const float*)d_in[0];
    const float* Wih1 = (const float*)d_in[1];
    const float* Whh1 = (const float*)d_in[2];
    const float* bih1 = (const float*)d_in[3];
    const float* bhh1 = (const float*)d_in[4];
    const float* Wih2 = (const float*)d_in[5];
    const float* Whh2 = (const float*)d_in[6];
    const float* bih2 = (const float*)d_in[7];
    const float* bhh2 = (const float*)d_in[8];
    const float* Wout = (const float*)d_in[9];
    const float* bout = (const float*)d_in[10];
    char* ws = (char*)d_ws;

    hipMemsetAsync(d_ws, 0, ZERO_BYTES, stream);
    prep_x<<<TSTEPS, 256, 0, stream>>>(inp, ws);
    lstm_persistent<<<NA + NB + NC, 256, 0, stream>>>(Wih1, Whh1, bih1, bhh1,
                                                      Wih2, Whh2, bih2, bhh2,
                                                      Wout, bout, ws, (float*)d_out);
}

// Round 4
// 5565.542 us; speedup vs baseline: 1.2708x; 1.2708x over previous
//
#include <hip/hip_runtime.h>
#include <hip/hip_fp16.h>

typedef _Float16 half8 __attribute__((ext_vector_type(8)));
typedef float    float4_ __attribute__((ext_vector_type(4)));

#define TSTEPS 512
#define NA 64
#define NB 128
#define NC 8
#define FSTRIDE 32                // ints per flag slot = 128 B (own cache line)

// workspace layout (bytes) — IDENTICAL to the proven R1 layout
#define FLA_OFF   0               // 64 flags  x 128 B
#define FLB_OFF   8192            // 128 flags x 128 B
#define FLC_OFF   24576           // 8 flags   x 128 B
#define H1_OFF    32768
#define H1_PHASE  262144          // 1024 cols x 128 batch x 2B, fragment-major
#define H2_OFF    (H1_OFF + 2 * H1_PHASE)
#define X_OFF     (H2_OFF + 2 * H1_PHASE)
#define X_TSTRIDE 16384           // 64 cols x 128 batch x 2B per step
#define ZERO_BYTES X_OFF          // flags + H1 + H2 zeroed each call

// fast activations: v_rcp_f32 (~1 ulp) + v_exp; h is stored fp16 anyway.
// Proven numerics-neutral in R3 (absmax identical to libm version).
__device__ __forceinline__ float fastrcp(float x) {
    float r; asm("v_rcp_f32 %0, %1" : "=v"(r) : "v"(x)); return r;
}
__device__ __forceinline__ float sigf(float x)  { return fastrcp(1.0f + __expf(-x)); }
__device__ __forceinline__ float tanh_(float x) { return 1.0f - 2.0f * fastrcp(1.0f + __expf(2.0f * x)); }

__device__ __forceinline__ half8 zero8() {
    half8 z;
#pragma unroll
    for (int j = 0; j < 8; ++j) z[j] = (_Float16)0.0f;
    return z;
}

__device__ __forceinline__ half8 wfrag_load(const float* Wa, int lda,
                                            const float* Wb, int ldb,
                                            int split, int row, int k0) {
    const float* s = (k0 < split) ? (Wa + (size_t)row * lda + k0)
                                  : (Wb + (size_t)row * ldb + (k0 - split));
    float4_ lo = *(const float4_*)s;
    float4_ hi = *(const float4_*)(s + 4);
    half8 r;
    r[0] = (_Float16)lo[0]; r[1] = (_Float16)lo[1];
    r[2] = (_Float16)lo[2]; r[3] = (_Float16)lo[3];
    r[4] = (_Float16)hi[0]; r[5] = (_Float16)hi[1];
    r[6] = (_Float16)hi[2]; r[7] = (_Float16)hi[3];
    return r;
}

// ---- coherence-point access primitives (NO fences, NO buffer_inv/wbl2) ----

// 16B device-scope-coherent plain load (sc1). Consumer must pass the value
// through a VMWAIT* fence below before use (compiler inserts no waitcnt).
__device__ __forceinline__ half8 ldg_sc1_16(const void* p) {
    half8 r;
    asm volatile("global_load_dwordx4 %0, %1, off sc1" : "=v"(r) : "v"(p));
    return r;
}

#define VMWAIT8(A) asm volatile("s_waitcnt vmcnt(0)" : \
    "+v"((A)[0]), "+v"((A)[1]), "+v"((A)[2]), "+v"((A)[3]), \
    "+v"((A)[4]), "+v"((A)[5]), "+v"((A)[6]), "+v"((A)[7]) :: "memory")

// counted waits: wait until at most N vmem ops outstanding, tying ONLY the
// group being released (loads complete in issue order).
#define VMWAIT9_N(A, NS) asm volatile("s_waitcnt vmcnt(" NS ")" : \
    "+v"((A)[0]), "+v"((A)[1]), "+v"((A)[2]), "+v"((A)[3]), "+v"((A)[4]), \
    "+v"((A)[5]), "+v"((A)[6]), "+v"((A)[7]), "+v"((A)[8]) :: "memory")
#define VMWAIT8_N(A, NS) asm volatile("s_waitcnt vmcnt(" NS ")" : \
    "+v"((A)[0]), "+v"((A)[1]), "+v"((A)[2]), "+v"((A)[3]), \
    "+v"((A)[4]), "+v"((A)[5]), "+v"((A)[6]), "+v"((A)[7]) :: "memory")

// 16B write-through store (sc0 sc1): full-line-coalescable publish store.
__device__ __forceinline__ void stg_coh_16(void* p, float4_ v) {
    asm volatile("global_store_dwordx4 %0, %1, off sc0 sc1" :: "v"(p), "v"(v) : "memory");
}

__device__ __forceinline__ void stg_coh_int(void* p, int v) {
    asm volatile("global_store_dword %0, %1, off sc0 sc1" :: "v"(p), "v"(v) : "memory");
}

// producer-side ordering: my write-through stores acked (vmcnt 0), then block
// barrier, then (thread 0) flag store.
__device__ __forceinline__ void publish(int* fbase, int idx, int v) {
    asm volatile("s_waitcnt vmcnt(0)" ::: "memory");
    __syncthreads();
    if (threadIdx.x == 0) stg_coh_int(fbase + idx * FSTRIDE, v);
}

__device__ __forceinline__ int ld_flag(const int* f, int idx) {
    return __hip_atomic_load(f + idx * FSTRIDE, __ATOMIC_RELAXED,
                             __HIP_MEMORY_SCOPE_AGENT);
}

// A-group: need all fA >= t (h1[t-1] ready) and all fB >= t-1 (phase free)
__device__ __forceinline__ void waitA(const int* fA, const int* fB, int t) {
    if (threadIdx.x < 64) {
        const int lane = threadIdx.x;
        for (;;) {
            int a  = ld_flag(fA, lane);
            int b0 = ld_flag(fB, lane);
            int b1 = ld_flag(fB, 64 + lane);
            if (__all((a >= t) && (b0 >= t - 1) && (b1 >= t - 1))) break;
            __builtin_amdgcn_s_sleep(1);
        }
    }
    __syncthreads();
}

// B-group: fA >= t+1 (h1[t]), fB >= t (h2[t-1]), fC >= t-1 (phase free)
__device__ __forceinline__ void waitB(const int* fA, const int* fB, const int* fC, int t) {
    if (threadIdx.x < 64) {
        const int lane = threadIdx.x;
        for (;;) {
            int a  = ld_flag(fA, lane);
            int b0 = ld_flag(fB, lane);
            int b1 = ld_flag(fB, 64 + lane);
            int c  = ld_flag(fC, lane & 7);
            if (__all((a >= t + 1) && (b0 >= t) && (b1 >= t) && (c >= t - 1))) break;
            __builtin_amdgcn_s_sleep(1);
        }
    }
    __syncthreads();
}

// C-group: fB >= t+1 (h2[t] ready)
__device__ __forceinline__ void waitC(const int* fB, int t) {
    if (threadIdx.x < 64) {
        const int lane = threadIdx.x;
        for (;;) {
            int b0 = ld_flag(fB, lane);
            int b1 = ld_flag(fB, 64 + lane);
            if (__all((b0 >= t + 1) && (b1 >= t + 1))) break;
            __builtin_amdgcn_s_sleep(1);
        }
    }
    __syncthreads();
}

// staging-image chunk swizzle: permutes 16B chunks, bank-spreads the
// per-column scattered 2B writes while keeping 16B read contiguity.
// Proven conflict-free and correct in R3.
__device__ __forceinline__ int swz(int u) {
    return u ^ (((u >> 3) ^ (u >> 7)) & 7);
}

// Convert input [128 b][512 t][64 i] fp32 -> fragment-major fp16 X[t][kt][quad][b][j]
extern "C" __global__ void prep_x(const float* __restrict__ in, char* __restrict__ ws) {
    const int t = blockIdx.x;
    char* X = ws + X_OFF + (size_t)t * X_TSTRIDE;
    for (int idx = threadIdx.x; idx < 8192; idx += 256) {
        int kt = idx >> 12, rem = idx & 4095;
        int quad = rem >> 10, rem2 = rem & 1023;
        int b = rem2 >> 3, j = rem2 & 7;
        int i = kt * 32 + quad * 8 + j;
        float v = in[(size_t)b * 32768 + (size_t)t * 64 + i];
        *(_Float16*)(X + (size_t)idx * 2) = (_Float16)v;
    }
}

extern "C" __global__ __launch_bounds__(256, 1)
void lstm_persistent(const float* __restrict__ Wih1, const float* __restrict__ Whh1,
                     const float* __restrict__ bih1, const float* __restrict__ bhh1,
                     const float* __restrict__ Wih2, const float* __restrict__ Whh2,
                     const float* __restrict__ bih2, const float* __restrict__ bhh2,
                     const float* __restrict__ Wout, const float* __restrict__ bout,
                     char* __restrict__ ws, float* __restrict__ out) {
    const int tid = threadIdx.x;
    const int w = tid >> 6, lane = tid & 63;
    const int quad = lane >> 4, cl = lane & 15;
    const int laneoff = quad * 2048 + cl * 16;
    int* fA = (int*)(ws + FLA_OFF);
    int* fB = (int*)(ws + FLB_OFF);
    int* fC = (int*)(ws + FLC_OFF);
    char* H1 = ws + H1_OFF;
    char* H2 = ws + H2_OFF;
    char* X  = ws + X_OFF;
    const int blk = blockIdx.x;
    __shared__ float redbuf[8192];                 // 32 KiB reduction scratch
    __shared__ __align__(16) unsigned short stg[2048];  // 4 KiB staging image

    if (blk < NA) {
        // ---------- layer-1: h1 cols [c0,c0+16), K = 1088 (34 k-tiles), waves split K
        const int c0 = blk * 16;
        const int kbase = w * 9;
        half8 wfr[4][9];
#pragma unroll
        for (int nt = 0; nt < 4; ++nt) {
            int row = nt * 1024 + c0 + cl;
#pragma unroll
            for (int kk = 0; kk < 9; ++kk) {
                int ktg = kbase + kk;
                if (ktg < 34) wfr[nt][kk] = wfrag_load(Wih1, 64, Whh1, 1024, 64, row, ktg * 32 + quad * 8);
                else          wfr[nt][kk] = zero8();
            }
        }
        float ba[4];
#pragma unroll
        for (int g = 0; g < 4; ++g) ba[g] = bih1[g * 1024 + c0 + cl] + bhh1[g * 1024 + c0 + cl];
        float cst[2][4];
#pragma unroll
        for (int mi = 0; mi < 2; ++mi)
#pragma unroll
            for (int r = 0; r < 4; ++r) cst[mi][r] = 0.0f;

        for (int t = 0; t < TSTEPS; ++t) {
            waitA(fA, fB, t);

            const char* xb  = X + (size_t)t * X_TSTRIDE;
            const char* h1r = H1 + (((t & 1) ^ 1) ? H1_PHASE : 0);
            char*       h1w = H1 + ((t & 1) ? H1_PHASE : 0);
            const char* kb[9];
#pragma unroll
            for (int kk = 0; kk < 9; ++kk) {
                int ktg = kbase + kk; if (ktg > 33) ktg = 33;
                kb[kk] = (ktg < 2) ? (xb + ktg * 8192) : (h1r + (ktg - 2) * 8192);
            }
            // 3-buffer, distance-2 prefetch with counted waits
            half8 af[3][9];
#pragma unroll
            for (int g = 0; g < 2; ++g)
#pragma unroll
                for (int kk = 0; kk < 9; ++kk)
                    af[g][kk] = ldg_sc1_16(kb[kk] + laneoff + g * 256);
            float4_ acc[8][4];
#pragma unroll
            for (int mt = 0; mt < 8; ++mt)
#pragma unroll
                for (int nt = 0; nt < 4; ++nt) acc[mt][nt] = (float4_){0.f, 0.f, 0.f, 0.f};
#pragma unroll
            for (int mt = 0; mt < 8; ++mt) {
                const int cur = mt % 3;
                if (mt < 7) { VMWAIT9_N(af[cur], "9"); }
                else        { VMWAIT9_N(af[cur], "0"); }
                if (mt < 6) {
                    const int nx = (mt + 2) % 3;
#pragma unroll
                    for (int kk = 0; kk < 9; ++kk)
                        af[nx][kk] = ldg_sc1_16(kb[kk] + laneoff + (mt + 2) * 256);
                }
#pragma unroll
                for (int kk = 0; kk < 9; ++kk)
#pragma unroll
                    for (int nt = 0; nt < 4; ++nt)
                        acc[mt][nt] = __builtin_amdgcn_mfma_f32_16x16x32_f16(
                            af[cur][kk], wfr[nt][kk], acc[mt][nt], 0, 0, 0);
            }
#pragma unroll
            for (int r = 0; r < 4; ++r) {
                if (w != r) {
#pragma unroll
                    for (int mi = 0; mi < 2; ++mi)
#pragma unroll
                        for (int nt = 0; nt < 4; ++nt)
                            *(float4_*)&redbuf[(((w * 2 + mi) * 4 + nt) * 64 + lane) * 4] = acc[2 * r + mi][nt];
                }
                __syncthreads();
                if (w == r) {
#pragma unroll
                    for (int wo = 0; wo < 4; ++wo) if (wo != r) {
#pragma unroll
                        for (int mi = 0; mi < 2; ++mi)
#pragma unroll
                            for (int nt = 0; nt < 4; ++nt)
                                acc[2 * r + mi][nt] += *(const float4_*)&redbuf[(((wo * 2 + mi) * 4 + nt) * 64 + lane) * 4];
                    }
                }
                __syncthreads();
            }
            float4_ mine[2][4];
#pragma unroll
            for (int r = 0; r < 4; ++r) if (w == r) {
#pragma unroll
                for (int mi = 0; mi < 2; ++mi)
#pragma unroll
                    for (int nt = 0; nt < 4; ++nt) mine[mi][nt] = acc[2 * r + mi][nt];
            }
            // nonlinearity -> swizzled staging image of the fragment-major dest
#pragma unroll
            for (int mi = 0; mi < 2; ++mi) {
#pragma unroll
                for (int r = 0; r < 4; ++r) {
                    float iv = mine[mi][0][r] + ba[0];
                    float fv = mine[mi][1][r] + ba[1];
                    float gv = mine[mi][2][r] + ba[2];
                    float ov = mine[mi][3][r] + ba[3];
                    float c = sigf(fv) * cst[mi][r] + sigf(iv) * tanh_(gv);
                    float h = sigf(ov) * tanh_(c);
                    cst[mi][r] = c;
                    int m = (2 * w + mi) * 16 + quad * 4 + r;
                    int u = ((cl >> 3) << 7) + m;
                    union { _Float16 hh; unsigned short us; } uu;
                    uu.hh = (_Float16)h;
                    stg[swz(u) * 8 + (cl & 7)] = uu.us;
                }
            }
            __syncthreads();
            // coalesced publish: one 16B full-line-combinable store per thread
            {
                const int g = tid >> 7, b = tid & 127;
                int u = (g << 7) + b;
                float4_ v = *(const float4_*)(stg + swz(u) * 8);
                char* dst = h1w + ((c0 >> 5) << 13) + ((((c0 >> 3) + g) & 3) << 11) + (b << 4);
                stg_coh_16(dst, v);
            }
            publish(fA, blk, t + 1);
        }
    } else if (blk < NA + NB) {
        // ---------- layer-2: h2 cols [c0,c0+8), K = 2048 (64 k-tiles), waves split K
        const int bb = blk - NA;
        const int c0 = bb * 8;
        const int kbase = w * 16;
        const int colB = c0 + (cl & 7);
        const int row0 = (cl < 8) ? colB : (1024 + colB);
        const int row1 = (cl < 8) ? (2048 + colB) : (3072 + colB);
        half8 wfr[2][16];
#pragma unroll
        for (int kk = 0; kk < 16; ++kk) {
            int k0 = (kbase + kk) * 32 + quad * 8;
            wfr[0][kk] = wfrag_load(Wih2, 1024, Whh2, 1024, 1024, row0, k0);
            wfr[1][kk] = wfrag_load(Wih2, 1024, Whh2, 1024, 1024, row1, k0);
        }
        const float bi = bih2[colB] + bhh2[colB];
        const float bf = bih2[1024 + colB] + bhh2[1024 + colB];
        const float bg = bih2[2048 + colB] + bhh2[2048 + colB];
        const float bo = bih2[3072 + colB] + bhh2[3072 + colB];
        float cst[2][4];
#pragma unroll
        for (int mi = 0; mi < 2; ++mi)
#pragma unroll
            for (int r = 0; r < 4; ++r) cst[mi][r] = 0.0f;
        const bool lolane = (cl & 8) == 0;

        for (int t = 0; t < TSTEPS; ++t) {
            waitB(fA, fB, fC, t);

            const char* h1c = H1 + ((t & 1) ? H1_PHASE : 0);
            const char* h2r = H2 + (((t & 1) ^ 1) ? H1_PHASE : 0);
            char*       h2w = H2 + ((t & 1) ? H1_PHASE : 0);
            const char* kb[16];
#pragma unroll
            for (int kk = 0; kk < 16; ++kk) {
                int ktg = kbase + kk;
                kb[kk] = (ktg < 32) ? (h1c + ktg * 8192) : (h2r + (ktg - 32) * 8192);
            }
            float4_ acc[8][2];
#pragma unroll
            for (int mt = 0; mt < 8; ++mt) {
                acc[mt][0] = (float4_){0.f, 0.f, 0.f, 0.f};
                acc[mt][1] = (float4_){0.f, 0.f, 0.f, 0.f};
            }
            // 4-buffer, sub-groups of 8 loads, distance-3 prefetch, counted waits.
            half8 af[4][8];
#pragma unroll
            for (int s = 0; s < 3; ++s)
#pragma unroll
                for (int k2 = 0; k2 < 8; ++k2)
                    af[s][k2] = ldg_sc1_16(kb[(s & 1) * 8 + k2] + laneoff + (s >> 1) * 256);
#pragma unroll
            for (int s = 0; s < 16; ++s) {
                const int cur = s & 3;
                if (s < 14)      { VMWAIT8_N(af[cur], "16"); }
                else if (s == 14){ VMWAIT8_N(af[cur], "8");  }
                else             { VMWAIT8_N(af[cur], "0");  }
                if (s < 13) {
                    const int nx = (s + 3) & 3;
#pragma unroll
                    for (int k2 = 0; k2 < 8; ++k2)
                        af[nx][k2] = ldg_sc1_16(kb[((s + 3) & 1) * 8 + k2] + laneoff + ((s + 3) >> 1) * 256);
                }
                const int mt = s >> 1, hb = (s & 1) * 8;
#pragma unroll
                for (int k2 = 0; k2 < 8; ++k2) {
                    acc[mt][0] = __builtin_amdgcn_mfma_f32_16x16x32_f16(af[cur][k2], wfr[0][hb + k2], acc[mt][0], 0, 0, 0);
                    acc[mt][1] = __builtin_amdgcn_mfma_f32_16x16x32_f16(af[cur][k2], wfr[1][hb + k2], acc[mt][1], 0, 0, 0);
                }
            }
#pragma unroll
            for (int r = 0; r < 4; ++r) {
                if (w != r) {
#pragma unroll
                    for (int mi = 0; mi < 2; ++mi)
#pragma unroll
                        for (int nt = 0; nt < 2; ++nt)
                            *(float4_*)&redbuf[(((w * 2 + mi) * 2 + nt) * 64 + lane) * 4] = acc[2 * r + mi][nt];
                }
                __syncthreads();
                if (w == r) {
#pragma unroll
                    for (int wo = 0; wo < 4; ++wo) if (wo != r) {
#pragma unroll
                        for (int mi = 0; mi < 2; ++mi)
#pragma unroll
                            for (int nt = 0; nt < 2; ++nt)
                                acc[2 * r + mi][nt] += *(const float4_*)&redbuf[(((wo * 2 + mi) * 2 + nt) * 64 + lane) * 4];
                    }
                }
                __syncthreads();
            }
            float4_ mine[2][2];
#pragma unroll
            for (int r = 0; r < 4; ++r) if (w == r) {
#pragma unroll
                for (int mi = 0; mi < 2; ++mi) {
                    mine[mi][0] = acc[2 * r + mi][0];
                    mine[mi][1] = acc[2 * r + mi][1];
                }
            }
#pragma unroll
            for (int mi = 0; mi < 2; ++mi) {
#pragma unroll
                for (int r = 0; r < 4; ++r) {
                    float d0 = mine[mi][0][r], d1 = mine[mi][1][r];
                    float s0 = __shfl_xor(d0, 8, 64);
                    float s1 = __shfl_xor(d1, 8, 64);
                    float iv = (lolane ? d0 : s0) + bi;
                    float fv = (lolane ? s0 : d0) + bf;
                    float gv = (lolane ? d1 : s1) + bg;
                    float ov = (lolane ? s1 : d1) + bo;
                    float c = sigf(fv) * cst[mi][r] + sigf(iv) * tanh_(gv);
                    float h = sigf(ov) * tanh_(c);
                    cst[mi][r] = c;
                    if (lolane) {
                        int m = (2 * w + mi) * 16 + quad * 4 + r;
                        union { _Float16 hh; unsigned short us; } uu;
                        uu.hh = (_Float16)h;
                        stg[swz(m) * 8 + (cl & 7)] = uu.us;
                    }
                }
            }
            __syncthreads();
            if (tid < 128) {
                const int b = tid;
                float4_ v = *(const float4_*)(stg + swz(b) * 8);
                char* dst = h2w + ((c0 >> 5) << 13) + (((c0 >> 3) & 3) << 11) + (b << 4);
                stg_coh_16(dst, v);
            }
            publish(fB, bb, t + 1);
        }
    } else {
        // ---------- output: batch tile cb, y = h2 @ Wout^T + bout, K = 1024
        const int cb = blk - NA - NB;
        const int kbase = w * 8;
        half8 wfr[4][8];
#pragma unroll
        for (int nt = 0; nt < 4; ++nt) {
            int row = nt * 16 + cl;
#pragma unroll
            for (int kk = 0; kk < 8; ++kk)
                wfr[nt][kk] = wfrag_load(Wout, 1024, Wout, 1024, 1 << 30, row, (kbase + kk) * 32 + quad * 8);
        }
        const float bo_ = bout[w * 16 + cl];

        for (int t = 0; t < TSTEPS; ++t) {
            waitC(fB, t);
            const char* h2c = H2 + ((t & 1) ? H1_PHASE : 0);
            float4_ acc[4];
#pragma unroll
            for (int nt = 0; nt < 4; ++nt) acc[nt] = (float4_){0.f, 0.f, 0.f, 0.f};
            half8 af[8];
#pragma unroll
            for (int kk = 0; kk < 8; ++kk)
                af[kk] = ldg_sc1_16(h2c + (kbase + kk) * 8192 + laneoff + cb * 256);
            VMWAIT8(af);
#pragma unroll
            for (int kk = 0; kk < 8; ++kk)
#pragma unroll
                for (int nt = 0; nt < 4; ++nt)
                    acc[nt] = __builtin_amdgcn_mfma_f32_16x16x32_f16(af[kk], wfr[nt][kk], acc[nt], 0, 0, 0);
#pragma unroll
            for (int r = 0; r < 4; ++r) {
                if (w != r) *(float4_*)&redbuf[(w * 64 + lane) * 4] = acc[r];
                __syncthreads();
                if (w == r) {
#pragma unroll
                    for (int wo = 0; wo < 4; ++wo) if (wo != r)
                        acc[r] += *(const float4_*)&redbuf[(wo * 64 + lane) * 4];
                }
                __syncthreads();
            }
            float4_ myy = acc[0];
#pragma unroll
            for (int r = 1; r < 4; ++r) if (w == r) myy = acc[r];
#pragma unroll
            for (int r = 0; r < 4; ++r) {
                int m = cb * 16 + quad * 4 + r;
                out[(size_t)m * 32768 + (size_t)t * 64 + (w * 16 + cl)] = myy[r] + bo_;
            }
            publish(fC, cb, t + 1);
        }
    }
}

extern "C" void kernel_launch(void* const* d_in, const int* in_sizes, int n_in,
                              void* d_out, int out_size, void* d_ws, size_t ws_size,
                              hipStream_t stream) {
    const float* inp  = (const float*)d_in[0];
    const float* Wih1 = (const float*)d_in[1];
    const float* Whh1 = (const float*)d_in[2];
    const float* bih1 = (const float*)d_in[3];
    const float* bhh1 = (const float*)d_in[4];
    const float* Wih2 = (const float*)d_in[5];
    const float* Whh2 = (const float*)d_in[6];
    const float* bih2 = (const float*)d_in[7];
    const float* bhh2 = (const float*)d_in[8];
    const float* Wout = (const float*)d_in[9];
    const float* bout = (const float*)d_in[10];
    char* ws = (char*)d_ws;

    hipMemsetAsync(d_ws, 0, ZERO_BYTES, stream);
    prep_x<<<TSTEPS, 256, 0, stream>>>(inp, ws);
    lstm_persistent<<<NA + NB + NC, 256, 0, stream>>>(Wih1, Whh1, bih1, bhh1,
                                                      Wih2, Whh2, bih2, bhh2,
                                                      Wout, bout, ws, (float*)d_out);
}